// Round 7
// baseline (1062.643 us; speedup 1.0000x reference)
//
#include <hip/hip_runtime.h>

#define BB 16
#define LL 2048
#define DD 768
#define KK 32
#define NEGI -1e30f

#define SCORE_BLOCKS (BB * LL / 4)     // 8192 blocks x 256 thr, 4 tokens each
#define BLOCKS_PER_B (SCORE_BLOCKS / BB)  // 512
#define POOL_UNITS (BB * KK * 3)       // 1536 (b,k,chunk) units, 1 wave each
#define POOL_BLOCKS (POOL_UNITS / 4)   // 384 blocks x 4 waves

// Fused kernel: blocks [0, 8192) score 4 tokens each and bump a per-batch
// counter (release). Blocks [8192, 8576) hold 4 pooler waves each; every wave
// waits (acquire) for its batch's 512 scorer blocks, then does span softmax +
// gather-pool exactly as R6's pool2_k. Deadlock-free by capacity: all 384
// pooler blocks fit co-resident on <=96 CUs (32 KB LDS each), so scorers
// always have CUs regardless of dispatch order.
__global__ __launch_bounds__(256) void fused_k(
    const float* __restrict__ th,
    const float* __restrict__ attn,
    const int* __restrict__ sps,
    const int* __restrict__ spe,
    const float* __restrict__ wp,
    const float* __restrict__ bp,
    float* __restrict__ scores,
    int* cnt,
    float* __restrict__ Hout,
    float* __restrict__ sent) {
  const int lane = threadIdx.x & 63;
  const int wave = threadIdx.x >> 6;
  const int g = blockIdx.x;

  __shared__ float lw[4][LL];  // 32 KB; poolers: one 8 KB weight buf per wave

  if (g < SCORE_BLOCKS) {
    // ---------------- scorer path ----------------
    const int token = (g << 2) + wave;   // < 32768
    const int b = token >> 11;           // /2048 (block-uniform: 512 blocks/batch)

    const float4* row = (const float4*)(th + (size_t)token * DD);
    const float4* wr  = (const float4*)wp;

    float4 a0 = row[lane], a1 = row[lane + 64], a2 = row[lane + 128];
    float4 w0 = wr[lane],  w1 = wr[lane + 64],  w2 = wr[lane + 128];

    float acc = 0.f;
    acc = fmaf(a0.x, w0.x, acc); acc = fmaf(a0.y, w0.y, acc);
    acc = fmaf(a0.z, w0.z, acc); acc = fmaf(a0.w, w0.w, acc);
    acc = fmaf(a1.x, w1.x, acc); acc = fmaf(a1.y, w1.y, acc);
    acc = fmaf(a1.z, w1.z, acc); acc = fmaf(a1.w, w1.w, acc);
    acc = fmaf(a2.x, w2.x, acc); acc = fmaf(a2.y, w2.y, acc);
    acc = fmaf(a2.z, w2.z, acc); acc = fmaf(a2.w, w2.w, acc);

    #pragma unroll
    for (int o = 32; o > 0; o >>= 1) acc += __shfl_xor(acc, o, 64);

    if (lane == 0) {
      float s = acc + bp[0];
      scores[token] = (attn[token] >= 0.5f) ? s : NEGI;
    }
    __threadfence();        // release: push score stores to device coherence point
    __syncthreads();        // all 4 waves' stores+fences done
    if (threadIdx.x == 0) atomicAdd(&cnt[b], 1);
    return;
  }

  // ---------------- pooler path: one wave per (b,k,chunk) unit ----------------
  const int unit = ((g - SCORE_BLOCKS) << 2) + wave;  // [0, 1536)
  const int bk = unit / 3;
  const int chunk = unit - bk * 3;
  const int b = bk >> 5;                              // K = 32
  float* mylw = lw[wave];

  int s0 = min(max(sps[bk], 0), LL);
  int e0 = min(max(spe[bk], 0), LL);

  // wait until all 512 scorer blocks of batch b have released their scores
  while (__hip_atomic_load(&cnt[b], __ATOMIC_ACQUIRE, __HIP_MEMORY_SCOPE_AGENT)
         < BLOCKS_PER_B) {
    __builtin_amdgcn_s_sleep(32);
  }
  __threadfence();  // acquire: invalidate stale L2 lines before plain loads

  const float* sc = scores + (size_t)b * LL;

  // span max
  float m = NEGI;
  for (int l = s0 + lane; l < e0; l += 64) m = fmaxf(m, sc[l]);
  #pragma unroll
  for (int o = 32; o > 0; o >>= 1) m = fmaxf(m, __shfl_xor(m, o, 64));

  // span exp-sum (masked tokens carry -1e30 -> contribute 0; all-masked -> ss=0)
  float ss = 0.f;
  for (int l = s0 + lane; l < e0; l += 64) {
    float v = sc[l];
    ss += (v > -1e29f) ? __expf(v - m) : 0.f;
  }
  #pragma unroll
  for (int o = 32; o > 0; o >>= 1) ss += __shfl_xor(ss, o, 64);

  const float inv = (ss > 0.f) ? (1.0f / ss) : 0.f;

  // normalized weights -> this wave's private LDS buffer (intra-wave only:
  // no __syncthreads needed; compiler inserts lgkmcnt waits)
  for (int l = s0 + lane; l < e0; l += 64) {
    float v = sc[l];
    mylw[l - s0] = (v > -1e29f) ? (__expf(v - m) * inv) : 0.f;
  }

  // gather-accumulate over span rows; lane owns 4 consecutive dims (16 B load)
  const float4* base = (const float4*)(th + (size_t)b * LL * DD + chunk * 256) + lane;
  float4 acc4 = make_float4(0.f, 0.f, 0.f, 0.f);
  #pragma unroll 8
  for (int l = s0; l < e0; ++l) {
    const float w = mylw[l - s0];
    float4 t = base[(size_t)l * (DD / 4)];
    acc4.x = fmaf(w, t.x, acc4.x);
    acc4.y = fmaf(w, t.y, acc4.y);
    acc4.z = fmaf(w, t.z, acc4.z);
    acc4.w = fmaf(w, t.w, acc4.w);
  }

  // direct store (empty / all-masked spans store zeros — matches reference)
  float4* o = (float4*)(Hout + (size_t)bk * DD + chunk * 256) + lane;
  *o = acc4;

  if (chunk == 0 && lane == 0) sent[bk] = (ss > 0.f) ? 1.0f : 0.0f;
}

extern "C" void kernel_launch(void* const* d_in, const int* in_sizes, int n_in,
                              void* d_out, int out_size, void* d_ws, size_t ws_size,
                              hipStream_t stream) {
  const float* th   = (const float*)d_in[0];  // [B,L,D] fp32
  const float* attn = (const float*)d_in[1];  // [B,L]   fp32
  const int*   sps  = (const int*)d_in[2];    // [B,K]
  const int*   spe  = (const int*)d_in[3];    // [B,K]
  const float* wp   = (const float*)d_in[4];  // [D]     fp32
  const float* bp   = (const float*)d_in[5];  // [1]     fp32

  float* Hout = (float*)d_out;                 // [B,K,D] then sent [B,K]
  float* sent = Hout + (size_t)BB * KK * DD;

  float* scores = (float*)d_ws;                // B*L fp32 (128 KB)
  int*   cnt    = (int*)(scores + (size_t)BB * LL);  // 16 ints

  hipMemsetAsync(cnt, 0, BB * sizeof(int), stream);  // counters must start at 0

  fused_k<<<dim3(SCORE_BLOCKS + POOL_BLOCKS), dim3(256), 0, stream>>>(
      th, attn, sps, spe, wp, bp, scores, cnt, Hout, sent);
}

// Round 8
// 167.874 us; speedup vs baseline: 6.3300x; 6.3300x over previous
//
#include <hip/hip_runtime.h>

#define BB 16
#define LL 2048
#define DD 768
#define KK 32
#define NEGI -1e30f
#define NW 16  // waves per block

// One block (16 waves) per (b,k) span. Single pass over the span's rows:
// each wave takes rows strided NW, computes the row's score inline
// (dot(row, w) — b_pool dropped: softmax is shift-invariant), and maintains
// online-softmax state (m, s, acc[768-distributed]) in registers. The 16
// wave-partials are merged through LDS at the end. token_hidden is read
// exactly once, only for span-covered rows; no workspace, no second kernel,
// no cross-workgroup sync (R7's agent-fence storm cost 10x — never again).
__global__ __launch_bounds__(1024) void span_pool_k(
    const float* __restrict__ th,
    const float* __restrict__ attn,
    const int* __restrict__ sps,
    const int* __restrict__ spe,
    const float* __restrict__ wp,
    float* __restrict__ Hout,
    float* __restrict__ sent) {
  const int bk = blockIdx.x;          // b*K + k
  const int b = bk >> 5;              // K = 32
  const int lane = threadIdx.x & 63;
  const int wave = threadIdx.x >> 6;

  __shared__ float sacc[NW][DD];      // 48 KB wave-partial accumulators
  __shared__ float sm[NW], ssm[NW];

  int s0 = min(max(sps[bk], 0), LL);
  int e0 = min(max(spe[bk], 0), LL);

  // pooling weights: lane owns dims {4*lane, 256+4*lane, 512+4*lane}+[0,3]
  const float4* wr = (const float4*)wp;
  const float4 w0 = wr[lane], w1 = wr[lane + 64], w2 = wr[lane + 128];

  const float* arow = attn + (size_t)b * LL;
  const float4* tb = (const float4*)(th + (size_t)b * LL * DD);

  float m = NEGI, s = 0.f;
  float4 a0 = make_float4(0.f, 0.f, 0.f, 0.f), a1 = a0, a2 = a0;

  #pragma unroll 2
  for (int l = s0 + wave; l < e0; l += NW) {
    const float4* row = tb + (size_t)l * (DD / 4);
    float4 r0 = row[lane], r1 = row[lane + 64], r2 = row[lane + 128];
    float am = arow[l];  // lane-uniform broadcast load

    float d = 0.f;
    d = fmaf(r0.x, w0.x, d); d = fmaf(r0.y, w0.y, d);
    d = fmaf(r0.z, w0.z, d); d = fmaf(r0.w, w0.w, d);
    d = fmaf(r1.x, w1.x, d); d = fmaf(r1.y, w1.y, d);
    d = fmaf(r1.z, w1.z, d); d = fmaf(r1.w, w1.w, d);
    d = fmaf(r2.x, w2.x, d); d = fmaf(r2.y, w2.y, d);
    d = fmaf(r2.z, w2.z, d); d = fmaf(r2.w, w2.w, d);
    #pragma unroll
    for (int o = 32; o > 0; o >>= 1) d += __shfl_xor(d, o, 64);

    if (am >= 0.5f) {  // wave-uniform (am identical across lanes)
      const float nm = fmaxf(m, d);
      const float sc = __expf(m - nm);   // first valid row: exp(-inf)=0
      const float e  = __expf(d - nm);
      s = fmaf(s, sc, e);
      a0.x = fmaf(e, r0.x, a0.x * sc); a0.y = fmaf(e, r0.y, a0.y * sc);
      a0.z = fmaf(e, r0.z, a0.z * sc); a0.w = fmaf(e, r0.w, a0.w * sc);
      a1.x = fmaf(e, r1.x, a1.x * sc); a1.y = fmaf(e, r1.y, a1.y * sc);
      a1.z = fmaf(e, r1.z, a1.z * sc); a1.w = fmaf(e, r1.w, a1.w * sc);
      a2.x = fmaf(e, r2.x, a2.x * sc); a2.y = fmaf(e, r2.y, a2.y * sc);
      a2.z = fmaf(e, r2.z, a2.z * sc); a2.w = fmaf(e, r2.w, a2.w * sc);
      m = nm;
    }
  }

  // publish wave partials
  float4* sa = (float4*)sacc[wave];
  sa[lane] = a0; sa[lane + 64] = a1; sa[lane + 128] = a2;
  if (lane == 0) { sm[wave] = m; ssm[wave] = s; }
  __syncthreads();

  // merge 16 wave-partials: acc_total = sum_w exp(m_w - M) * acc_w, etc.
  const int t = threadIdx.x;
  if (t < DD / 4) {
    float M = NEGI;
    #pragma unroll
    for (int w = 0; w < NW; ++w) M = fmaxf(M, sm[w]);
    float S = 0.f;
    #pragma unroll
    for (int w = 0; w < NW; ++w) S = fmaf(__expf(sm[w] - M), ssm[w], S);
    const float inv = (S > 0.f) ? (1.0f / S) : 0.f;  // empty/all-masked -> 0

    float4 o = make_float4(0.f, 0.f, 0.f, 0.f);
    #pragma unroll
    for (int w = 0; w < NW; ++w) {
      const float ew = __expf(sm[w] - M);  // empty wave: s=0, acc=0 -> no-op
      const float4 p = ((const float4*)sacc[w])[t];
      o.x = fmaf(ew, p.x, o.x); o.y = fmaf(ew, p.y, o.y);
      o.z = fmaf(ew, p.z, o.z); o.w = fmaf(ew, p.w, o.w);
    }
    o.x *= inv; o.y *= inv; o.z *= inv; o.w *= inv;
    ((float4*)(Hout + (size_t)bk * DD))[t] = o;   // all 768 dims always written
    if (t == 0) sent[bk] = (S > 0.f) ? 1.0f : 0.0f;
  }
}

extern "C" void kernel_launch(void* const* d_in, const int* in_sizes, int n_in,
                              void* d_out, int out_size, void* d_ws, size_t ws_size,
                              hipStream_t stream) {
  const float* th   = (const float*)d_in[0];  // [B,L,D] fp32
  const float* attn = (const float*)d_in[1];  // [B,L]   fp32
  const int*   sps  = (const int*)d_in[2];    // [B,K]
  const int*   spe  = (const int*)d_in[3];    // [B,K]
  const float* wp   = (const float*)d_in[4];  // [D]     fp32
  // d_in[5] (b_pool) intentionally unused: softmax(x + c) == softmax(x)

  float* Hout = (float*)d_out;                 // [B,K,D] then sent [B,K]
  float* sent = Hout + (size_t)BB * KK * DD;

  span_pool_k<<<dim3(BB * KK), dim3(1024), 0, stream>>>(
      th, attn, sps, spe, wp, Hout, sent);
}